// Round 1
// baseline (316.362 us; speedup 1.0000x reference)
//
#include <hip/hip_runtime.h>

typedef unsigned short u16;
typedef __bf16 bf16x8 __attribute__((ext_vector_type(8)));
typedef float f32x4 __attribute__((ext_vector_type(4)));

// ---------- bf16 <-> f32 helpers (RNE), no hip_bf16.h dependence ----------
__device__ __forceinline__ u16 f2bf(float f) {
    union { float f; unsigned int u; } v; v.f = f;
    unsigned int u = v.u;
    unsigned int r = (u + 0x7FFFu + ((u >> 16) & 1u)) >> 16;
    return (u16)r;
}
__device__ __forceinline__ float bf2f(u16 h) {
    union { unsigned int u; float f; } v; v.u = ((unsigned int)h) << 16;
    return v.f;
}

// ---------- async global->LDS, 16B per lane ----------
__device__ __forceinline__ void load_lds16(const void* g, void* l) {
    __builtin_amdgcn_global_load_lds(
        (const __attribute__((address_space(1))) unsigned int*)g,
        (__attribute__((address_space(3))) unsigned int*)l,
        16, 0, 0);
}

// ---------------------------------------------------------------
// prep: cast x (fp32) -> bf16, 4 elems/thread
// ---------------------------------------------------------------
__global__ void __launch_bounds__(256) cast_x_kernel(const float4* __restrict__ X,
                                                     u16* __restrict__ out) {
    int idx = blockIdx.x * 256 + threadIdx.x;   // 2M float4s
    float4 v = X[idx];
    ushort4 o;
    o.x = f2bf(v.x); o.y = f2bf(v.y); o.z = f2bf(v.z); o.w = f2bf(v.w);
    *(ushort4*)(out + (size_t)idx * 4) = o;
}

// ---------------------------------------------------------------
// prep: transpose + cast W [1024,1024] fp32 -> Wt [n][k] bf16
// ---------------------------------------------------------------
__global__ void __launch_bounds__(256) transpose_w_kernel(
    const float* __restrict__ W0, const float* __restrict__ W1, const float* __restrict__ W2,
    u16* __restrict__ O0, u16* __restrict__ O1, u16* __restrict__ O2) {
    const float* W = (blockIdx.z == 0) ? W0 : (blockIdx.z == 1) ? W1 : W2;
    u16* O = (blockIdx.z == 0) ? O0 : (blockIdx.z == 1) ? O1 : O2;
    __shared__ float tile[32][33];
    int tx = threadIdx.x, ty = threadIdx.y;
    int n0 = blockIdx.x * 32, k0 = blockIdx.y * 32;
    #pragma unroll
    for (int j = 0; j < 32; j += 8)
        tile[ty + j][tx] = W[(size_t)(k0 + ty + j) * 1024 + n0 + tx];
    __syncthreads();
    #pragma unroll
    for (int j = 0; j < 32; j += 8)
        O[(size_t)(n0 + ty + j) * 1024 + k0 + tx] = f2bf(tile[tx][ty + j]);
}

// ---------------------------------------------------------------
// Generic NT bf16 GEMM: C[m,n] = sum_k A[m,k]*B[n,k], lda=ldb=K.
// 128x128 tile, BK=32, 256 threads (4 waves in 2x2), mfma 16x16x32 bf16.
// MODE 0: bf16 out, row-major ldc=N                (Q, K projections)
// MODE 1: bf16 out * cscale, skip tiles above diag (scores)
// MODE 2: bf16 out, Vt mapping: C[m,n]->Vt[b][m][n&2047], b=n>>11
// MODE 3: fp32 out, ldc=N, K-loop clipped causally (PV)
// ---------------------------------------------------------------
template <int MODE>
__global__ void __launch_bounds__(256) gemm_nt(
    const u16* __restrict__ A, const u16* __restrict__ B, void* __restrict__ Cv,
    int M, int N, int K, long sA, long sB, long sC, float cscale) {
    const int z = blockIdx.z;
    A += (size_t)z * sA;
    B += (size_t)z * sB;

    const int mtile = blockIdx.y, ntile = blockIdx.x;
    if (MODE == 1 && ntile > mtile) return;   // fully-masked score tile

    __shared__ __align__(16) u16 As[128 * 32];
    __shared__ __align__(16) u16 Bs[128 * 32];

    const int tid = threadIdx.x;
    const int lane = tid & 63;
    const int wave = tid >> 6;
    const int wr = wave >> 1, wc = wave & 1;

    int ktiles = K >> 5;
    if (MODE == 3) ktiles = (mtile + 1) * 4;  // causal K clip (BK=32, BM=128)

    // staging: 128 rows x 64B per tile = 2 rounds x (256 lanes x 16B)
    const int r0 = tid >> 2;              // 0..63
    const int kb = (tid & 3) * 16;        // byte within 64B k-slab
    const char* gA0 = (const char*)(A + (size_t)(mtile * 128 + r0) * K) + kb;
    const char* gA1 = (const char*)(A + (size_t)(mtile * 128 + 64 + r0) * K) + kb;
    const char* gB0 = (const char*)(B + (size_t)(ntile * 128 + r0) * K) + kb;
    const char* gB1 = (const char*)(B + (size_t)(ntile * 128 + 64 + r0) * K) + kb;
    char* lA0 = (char*)As + tid * 16;
    char* lA1 = (char*)As + 4096 + tid * 16;
    char* lB0 = (char*)Bs + tid * 16;
    char* lB1 = (char*)Bs + 4096 + tid * 16;

    f32x4 acc[4][4] = {};

    const int quad = lane >> 4;   // 0..3
    const int l16 = lane & 15;
    const u16* aptr = As + (wr * 64 + l16) * 32 + quad * 8;
    const u16* bptr = Bs + (wc * 64 + l16) * 32 + quad * 8;

    for (int kt = 0; kt < ktiles; ++kt) {
        load_lds16(gA0, lA0); load_lds16(gA1, lA1);
        load_lds16(gB0, lB0); load_lds16(gB1, lB1);
        gA0 += 64; gA1 += 64; gB0 += 64; gB1 += 64;
        __syncthreads();   // drains vmcnt(0) -> staged data visible

        bf16x8 af[4], bfv[4];
        #pragma unroll
        for (int r = 0; r < 4; ++r) af[r] = *(const bf16x8*)(aptr + r * 16 * 32);
        #pragma unroll
        for (int c = 0; c < 4; ++c) bfv[c] = *(const bf16x8*)(bptr + c * 16 * 32);
        #pragma unroll
        for (int r = 0; r < 4; ++r)
            #pragma unroll
            for (int c = 0; c < 4; ++c)
                acc[r][c] = __builtin_amdgcn_mfma_f32_16x16x32_bf16(af[r], bfv[c], acc[r][c], 0, 0, 0);
        __syncthreads();   // all waves done reading before next stage
    }

    // epilogue — C/D layout: col = lane&15, row = (lane>>4)*4 + reg
    const int grow0 = mtile * 128 + wr * 64 + quad * 4;
    const int gcol0 = ntile * 128 + wc * 64 + l16;

    if (MODE == 0 || MODE == 1) {
        u16* C = (u16*)Cv + (size_t)z * sC;
        #pragma unroll
        for (int r = 0; r < 4; ++r)
            #pragma unroll
            for (int c = 0; c < 4; ++c)
                #pragma unroll
                for (int i = 0; i < 4; ++i) {
                    int grow = grow0 + r * 16 + i;
                    int gcol = gcol0 + c * 16;
                    C[(size_t)grow * N + gcol] = f2bf(acc[r][c][i] * cscale);
                }
    } else if (MODE == 2) {
        u16* C = (u16*)Cv;
        #pragma unroll
        for (int r = 0; r < 4; ++r)
            #pragma unroll
            for (int c = 0; c < 4; ++c)
                #pragma unroll
                for (int i = 0; i < 4; ++i) {
                    int grow = grow0 + r * 16 + i;       // d index
                    int gcol = gcol0 + c * 16;           // global s index
                    int b = gcol >> 11, sc = gcol & 2047;
                    C[(size_t)b * (1024 * 2048) + (size_t)grow * 2048 + sc] =
                        f2bf(acc[r][c][i]);
                }
    } else {  // MODE 3
        float* C = (float*)Cv + (size_t)z * sC;
        #pragma unroll
        for (int r = 0; r < 4; ++r)
            #pragma unroll
            for (int c = 0; c < 4; ++c)
                #pragma unroll
                for (int i = 0; i < 4; ++i) {
                    int grow = grow0 + r * 16 + i;
                    int gcol = gcol0 + c * 16;
                    C[(size_t)grow * N + gcol] = acc[r][c][i];
                }
    }
}

// ---------------------------------------------------------------
// softmax over causal rows, in place on bf16 scores (already *1/32).
// One 256-thread block per row. Applies causal mask BY INDEX (never
// reads the unwritten upper triangle). Writes zeros up to the row's
// 128-block boundary so PV's clipped K-loop reads only defined data.
// ---------------------------------------------------------------
__global__ void __launch_bounds__(256) softmax_rows(u16* __restrict__ S) {
    const int row = blockIdx.x;
    const int b = row >> 11, i = row & 2047;
    u16* Srow = S + (size_t)b * (2048 * 2048) + (size_t)i * 2048;
    const int limit = ((i >> 7) + 1) << 7;
    const int tid = threadIdx.x;

    float xs[8];
    float lmax = -3.0e38f;
    #pragma unroll
    for (int t = 0; t < 8; ++t) {
        int j = tid + t * 256;
        float v = -3.0e38f;
        if (j <= i) v = bf2f(Srow[j]);
        xs[t] = v;
        lmax = fmaxf(lmax, v);
    }
    #pragma unroll
    for (int off = 32; off >= 1; off >>= 1)
        lmax = fmaxf(lmax, __shfl_xor(lmax, off, 64));
    __shared__ float redm[4], reds[4];
    if ((tid & 63) == 0) redm[tid >> 6] = lmax;
    __syncthreads();
    float bmax = fmaxf(fmaxf(redm[0], redm[1]), fmaxf(redm[2], redm[3]));

    float es[8];
    float lsum = 0.f;
    #pragma unroll
    for (int t = 0; t < 8; ++t) {
        int j = tid + t * 256;
        float e = 0.f;
        if (j <= i) e = __expf(xs[t] - bmax);
        es[t] = e;
        lsum += e;
    }
    #pragma unroll
    for (int off = 32; off >= 1; off >>= 1)
        lsum += __shfl_xor(lsum, off, 64);
    if ((tid & 63) == 0) reds[tid >> 6] = lsum;
    __syncthreads();
    float inv = 1.f / (reds[0] + reds[1] + reds[2] + reds[3]);

    #pragma unroll
    for (int t = 0; t < 8; ++t) {
        int j = tid + t * 256;
        if (j < limit) Srow[j] = f2bf(es[t] * inv);
    }
}

// ---------------------------------------------------------------
// launch
// ---------------------------------------------------------------
extern "C" void kernel_launch(void* const* d_in, const int* in_sizes, int n_in,
                              void* d_out, int out_size, void* d_ws, size_t ws_size,
                              hipStream_t stream) {
    const float* x  = (const float*)d_in[0];
    const float* Wq = (const float*)d_in[1];
    const float* Wk = (const float*)d_in[2];
    const float* Wv = (const float*)d_in[3];
    float* out = (float*)d_out;
    char* ws = (char*)d_ws;
    const size_t Mi = 1u << 20;

    u16* xb  = (u16*)(ws);               // [8192][1024] bf16  16 MiB
    u16* WqT = (u16*)(ws + 16 * Mi);     // [1024][1024] bf16   2 MiB
    u16* WkT = (u16*)(ws + 18 * Mi);
    u16* WvT = (u16*)(ws + 20 * Mi);
    u16* Q   = (u16*)(ws + 22 * Mi);     // [8192][1024] bf16  16 MiB
    u16* Kb  = (u16*)(ws + 38 * Mi);
    u16* Vt  = (u16*)(ws + 54 * Mi);     // [4][1024][2048] bf16 16 MiB
    u16* S   = (u16*)(ws + 70 * Mi);     // [4][2048][2048] bf16 32 MiB

    // prep
    cast_x_kernel<<<8192, 256, 0, stream>>>((const float4*)x, xb);
    transpose_w_kernel<<<dim3(32, 32, 3), dim3(32, 8), 0, stream>>>(
        Wq, Wk, Wv, WqT, WkT, WvT);

    // QKV projections
    gemm_nt<0><<<dim3(8, 64, 1), 256, 0, stream>>>(xb, WqT, Q, 8192, 1024, 1024, 0, 0, 0, 1.f);
    gemm_nt<0><<<dim3(8, 64, 1), 256, 0, stream>>>(xb, WkT, Kb, 8192, 1024, 1024, 0, 0, 0, 1.f);
    gemm_nt<2><<<dim3(64, 8, 1), 256, 0, stream>>>(WvT, xb, Vt, 1024, 8192, 1024, 0, 0, 0, 1.f);

    // scores = (Q K^T) / 32, causal tiles only
    gemm_nt<1><<<dim3(16, 16, 4), 256, 0, stream>>>(
        Q, Kb, S, 2048, 2048, 1024,
        (long)2048 * 1024, (long)2048 * 1024, (long)2048 * 2048, 0.03125f);

    // softmax in place
    softmax_rows<<<8192, 256, 0, stream>>>(S);

    // O = P V  (K-loop causally clipped)
    gemm_nt<3><<<dim3(8, 16, 4), 256, 0, stream>>>(
        S, Vt, out, 2048, 1024, 2048,
        (long)2048 * 2048, (long)1024 * 2048, (long)2048 * 1024, 1.f);
}

// Round 2
// 268.036 us; speedup vs baseline: 1.1803x; 1.1803x over previous
//
#include <hip/hip_runtime.h>

typedef unsigned short u16;
typedef __bf16 bf16x8 __attribute__((ext_vector_type(8)));
typedef float f32x4 __attribute__((ext_vector_type(4)));

// ---------- bf16 <-> f32 helpers (RNE) ----------
__device__ __forceinline__ u16 f2bf(float f) {
    union { float f; unsigned int u; } v; v.f = f;
    unsigned int u = v.u;
    return (u16)((u + 0x7FFFu + ((u >> 16) & 1u)) >> 16);
}
__device__ __forceinline__ float bf2f(u16 h) {
    union { unsigned int u; float f; } v; v.u = ((unsigned int)h) << 16;
    return v.f;
}

// ---------- async global->LDS, 16B per lane ----------
__device__ __forceinline__ void load_lds16(const void* g, void* l) {
    __builtin_amdgcn_global_load_lds(
        (const __attribute__((address_space(1))) unsigned int*)g,
        (__attribute__((address_space(3))) unsigned int*)l,
        16, 0, 0);
}

// ---------------------------------------------------------------
// prep: cast x (fp32) -> bf16
// ---------------------------------------------------------------
__global__ void __launch_bounds__(256) cast_x_kernel(const float4* __restrict__ X,
                                                     u16* __restrict__ out) {
    int idx = blockIdx.x * 256 + threadIdx.x;
    float4 v = X[idx];
    ushort4 o;
    o.x = f2bf(v.x); o.y = f2bf(v.y); o.z = f2bf(v.z); o.w = f2bf(v.w);
    *(ushort4*)(out + (size_t)idx * 4) = o;
}

// ---------------------------------------------------------------
// prep: transpose + cast W [1024,1024] fp32 -> Wt [n][k] bf16
// ---------------------------------------------------------------
__global__ void __launch_bounds__(256) transpose_w_kernel(
    const float* __restrict__ W0, const float* __restrict__ W1, const float* __restrict__ W2,
    u16* __restrict__ O0, u16* __restrict__ O1, u16* __restrict__ O2) {
    const float* W = (blockIdx.z == 0) ? W0 : (blockIdx.z == 1) ? W1 : W2;
    u16* O = (blockIdx.z == 0) ? O0 : (blockIdx.z == 1) ? O1 : O2;
    __shared__ float tile[32][33];
    int tx = threadIdx.x, ty = threadIdx.y;
    int n0 = blockIdx.x * 32, k0 = blockIdx.y * 32;
    #pragma unroll
    for (int j = 0; j < 32; j += 8)
        tile[ty + j][tx] = W[(size_t)(k0 + ty + j) * 1024 + n0 + tx];
    __syncthreads();
    #pragma unroll
    for (int j = 0; j < 32; j += 8)
        O[(size_t)(n0 + ty + j) * 1024 + k0 + tx] = f2bf(tile[tx][ty + j]);
}

// ---------------------------------------------------------------
// NT bf16 GEMM, 128x128 tile, BK=64 (two 32-K LDS buffer pairs staged
// together -> one barrier per 32 MFMAs), XOR-swizzled LDS chunks
// (chunk = quad ^ ((row>>1)&3)) -> conflict-free ds_read_b128.
//
// MODE 0: merged QKV. z selects B (WqT/WkT/WvT) and C (Q / K / Vt).
//         z<2: bf16 row-major [8192][1024]; z==2: Vt[b][d][s] store.
// MODE 1: scores = (Q K^T)*cscale, bf16 out, skip tiles above diagonal.
// MODE 3: PV, fp32 out, K-loop causally clipped.
// ---------------------------------------------------------------
template <int MODE>
__global__ void __launch_bounds__(256) gemm_nt(
    const u16* __restrict__ A, const u16* __restrict__ Bq,
    const u16* __restrict__ Bk, const u16* __restrict__ Bv,
    void* __restrict__ Cq, void* __restrict__ Ck, void* __restrict__ Cv,
    int M, int N, int K, long sA, long sB, long sC, float cscale) {
    const int z = blockIdx.z;
    const u16* B;
    if (MODE == 0) {
        B = (z == 0) ? Bq : (z == 1) ? Bk : Bv;
    } else {
        B = Bq + (size_t)z * sB;
        A += (size_t)z * sA;
    }

    const int mtile = blockIdx.y, ntile = blockIdx.x;
    if (MODE == 1 && ntile > mtile) return;

    __shared__ __align__(16) u16 As[2][128 * 32];
    __shared__ __align__(16) u16 Bs[2][128 * 32];

    const int tid = threadIdx.x;
    const int lane = tid & 63;
    const int wave = tid >> 6;
    const int wr = wave >> 1, wc = wave & 1;

    int kiters = K >> 6;                      // BK = 64
    if (MODE == 3) kiters = (mtile + 1) * 2;  // causal clip (BM=128)

    // staging: lane -> row r0 = tid>>2 (and r0+64), LDS chunk c_l = tid&3,
    // fetches global chunk c_l ^ ((r0>>1)&3)  (swizzle, row-stable mod 64/16)
    const int r0 = tid >> 2;
    const int kb = (((tid & 3) ^ ((r0 >> 1) & 3))) * 16;  // byte offset in 64B slab

    const char* gA0 = (const char*)(A + (size_t)(mtile * 128 + r0) * K) + kb;
    const char* gA1 = gA0 + (size_t)64 * K * 2;
    const char* gB0 = (const char*)(B + (size_t)(ntile * 128 + r0) * K) + kb;
    const char* gB1 = gB0 + (size_t)64 * K * 2;

    char* lA = (char*)(&As[0][0]) + tid * 16;  // buf0 rows 0-63; +4096 rows 64-127; +8192 buf1
    char* lB = (char*)(&Bs[0][0]) + tid * 16;

    f32x4 acc[4][4] = {};

    const int quad = lane >> 4;
    const int l16 = lane & 15;
    const int ch = quad ^ ((l16 >> 1) & 3);   // de-swizzle on read
    const int aoff = (wr * 64 + l16) * 32 + ch * 8;
    const int boff = (wc * 64 + l16) * 32 + ch * 8;

    for (int kt = 0; kt < kiters; ++kt) {
        load_lds16(gA0,      lA);
        load_lds16(gA1,      lA + 4096);
        load_lds16(gA0 + 64, lA + 8192);
        load_lds16(gA1 + 64, lA + 12288);
        load_lds16(gB0,      lB);
        load_lds16(gB1,      lB + 4096);
        load_lds16(gB0 + 64, lB + 8192);
        load_lds16(gB1 + 64, lB + 12288);
        gA0 += 128; gA1 += 128; gB0 += 128; gB1 += 128;
        __syncthreads();

        #pragma unroll
        for (int h = 0; h < 2; ++h) {
            const u16* ap = &As[h][aoff];
            const u16* bp = &Bs[h][boff];
            bf16x8 af[4], bfv[4];
            #pragma unroll
            for (int r = 0; r < 4; ++r) af[r] = *(const bf16x8*)(ap + r * 512);
            #pragma unroll
            for (int c = 0; c < 4; ++c) bfv[c] = *(const bf16x8*)(bp + c * 512);
            #pragma unroll
            for (int r = 0; r < 4; ++r)
                #pragma unroll
                for (int c = 0; c < 4; ++c)
                    acc[r][c] = __builtin_amdgcn_mfma_f32_16x16x32_bf16(af[r], bfv[c], acc[r][c], 0, 0, 0);
        }
        __syncthreads();
    }

    // epilogue — C/D layout: col = lane&15, row = (lane>>4)*4 + reg
    const int grow0 = mtile * 128 + wr * 64 + quad * 4;
    const int gcol0 = ntile * 128 + wc * 64 + l16;

    if (MODE == 0) {
        if (z < 2) {
            u16* C = (u16*)((z == 0) ? Cq : Ck);
            #pragma unroll
            for (int r = 0; r < 4; ++r)
                #pragma unroll
                for (int c = 0; c < 4; ++c)
                    #pragma unroll
                    for (int i = 0; i < 4; ++i)
                        C[(size_t)(grow0 + r * 16 + i) * N + gcol0 + c * 16] =
                            f2bf(acc[r][c][i]);
        } else {
            // Vt[b][d][s]: m -> (b, s), n -> d; 4 consecutive i -> consecutive s
            u16* C = (u16*)Cv;
            #pragma unroll
            for (int r = 0; r < 4; ++r) {
                int m0 = grow0 + r * 16;
                int b = m0 >> 11, s0 = m0 & 2047;
                #pragma unroll
                for (int c = 0; c < 4; ++c) {
                    int d = gcol0 + c * 16;
                    ushort4 o;
                    o.x = f2bf(acc[r][c][0]); o.y = f2bf(acc[r][c][1]);
                    o.z = f2bf(acc[r][c][2]); o.w = f2bf(acc[r][c][3]);
                    *(ushort4*)(C + (size_t)b * (1024 * 2048) + (size_t)d * 2048 + s0) = o;
                }
            }
        }
    } else if (MODE == 1) {
        u16* C = (u16*)Cq + (size_t)z * sC;
        #pragma unroll
        for (int r = 0; r < 4; ++r)
            #pragma unroll
            for (int c = 0; c < 4; ++c)
                #pragma unroll
                for (int i = 0; i < 4; ++i)
                    C[(size_t)(grow0 + r * 16 + i) * N + gcol0 + c * 16] =
                        f2bf(acc[r][c][i] * cscale);
    } else {
        float* C = (float*)Cq + (size_t)z * sC;
        #pragma unroll
        for (int r = 0; r < 4; ++r)
            #pragma unroll
            for (int c = 0; c < 4; ++c)
                #pragma unroll
                for (int i = 0; i < 4; ++i)
                    C[(size_t)(grow0 + r * 16 + i) * N + gcol0 + c * 16] = acc[r][c][i];
    }
}

// ---------------------------------------------------------------
// softmax over causal rows, in place on bf16 scores.
// Mask applied BY INDEX; zero-fills to the row's 128-block boundary.
// ---------------------------------------------------------------
__global__ void __launch_bounds__(256) softmax_rows(u16* __restrict__ S) {
    const int row = blockIdx.x;
    const int b = row >> 11, i = row & 2047;
    u16* Srow = S + (size_t)b * (2048 * 2048) + (size_t)i * 2048;
    const int limit = ((i >> 7) + 1) << 7;
    const int tid = threadIdx.x;

    float xs[8];
    float lmax = -3.0e38f;
    #pragma unroll
    for (int t = 0; t < 8; ++t) {
        int j = tid + t * 256;
        float v = -3.0e38f;
        if (j <= i) v = bf2f(Srow[j]);
        xs[t] = v;
        lmax = fmaxf(lmax, v);
    }
    #pragma unroll
    for (int off = 32; off >= 1; off >>= 1)
        lmax = fmaxf(lmax, __shfl_xor(lmax, off, 64));
    __shared__ float redm[4], reds[4];
    if ((tid & 63) == 0) redm[tid >> 6] = lmax;
    __syncthreads();
    float bmax = fmaxf(fmaxf(redm[0], redm[1]), fmaxf(redm[2], redm[3]));

    float es[8];
    float lsum = 0.f;
    #pragma unroll
    for (int t = 0; t < 8; ++t) {
        int j = tid + t * 256;
        float e = 0.f;
        if (j <= i) e = __expf(xs[t] - bmax);
        es[t] = e;
        lsum += e;
    }
    #pragma unroll
    for (int off = 32; off >= 1; off >>= 1)
        lsum += __shfl_xor(lsum, off, 64);
    if ((tid & 63) == 0) reds[tid >> 6] = lsum;
    __syncthreads();
    float inv = 1.f / (reds[0] + reds[1] + reds[2] + reds[3]);

    #pragma unroll
    for (int t = 0; t < 8; ++t) {
        int j = tid + t * 256;
        if (j < limit) Srow[j] = f2bf(es[t] * inv);
    }
}

// ---------------------------------------------------------------
// launch
// ---------------------------------------------------------------
extern "C" void kernel_launch(void* const* d_in, const int* in_sizes, int n_in,
                              void* d_out, int out_size, void* d_ws, size_t ws_size,
                              hipStream_t stream) {
    const float* x  = (const float*)d_in[0];
    const float* Wq = (const float*)d_in[1];
    const float* Wk = (const float*)d_in[2];
    const float* Wv = (const float*)d_in[3];
    float* out = (float*)d_out;
    char* ws = (char*)d_ws;
    const size_t Mi = 1u << 20;

    u16* xb  = (u16*)(ws);               // [8192][1024] bf16  16 MiB
    u16* WqT = (u16*)(ws + 16 * Mi);     // [1024][1024] bf16   2 MiB
    u16* WkT = (u16*)(ws + 18 * Mi);
    u16* WvT = (u16*)(ws + 20 * Mi);
    u16* Q   = (u16*)(ws + 22 * Mi);     // [8192][1024] bf16  16 MiB
    u16* Kb  = (u16*)(ws + 38 * Mi);
    u16* Vt  = (u16*)(ws + 54 * Mi);     // [4][1024][2048] bf16 16 MiB
    u16* S   = (u16*)(ws + 70 * Mi);     // [4][2048][2048] bf16 32 MiB

    cast_x_kernel<<<8192, 256, 0, stream>>>((const float4*)x, xb);
    transpose_w_kernel<<<dim3(32, 32, 3), dim3(32, 8), 0, stream>>>(
        Wq, Wk, Wv, WqT, WkT, WvT);

    // merged QKV projections (z: 0=Q, 1=K, 2=Vt), 1536 blocks
    gemm_nt<0><<<dim3(8, 64, 3), 256, 0, stream>>>(
        xb, WqT, WkT, WvT, Q, Kb, Vt, 8192, 1024, 1024, 0, 0, 0, 1.f);

    // scores = (Q K^T)/32, causal tiles only
    gemm_nt<1><<<dim3(16, 16, 4), 256, 0, stream>>>(
        Q, Kb, nullptr, nullptr, S, nullptr, nullptr, 2048, 2048, 1024,
        (long)2048 * 1024, (long)2048 * 1024, (long)2048 * 2048, 0.03125f);

    softmax_rows<<<8192, 256, 0, stream>>>(S);

    // O = P V  (K-loop causally clipped)
    gemm_nt<3><<<dim3(8, 16, 4), 256, 0, stream>>>(
        S, Vt, nullptr, nullptr, out, nullptr, nullptr, 2048, 1024, 2048,
        (long)2048 * 2048, (long)1024 * 2048, (long)2048 * 1024, 1.f);
}

// Round 3
// 237.531 us; speedup vs baseline: 1.3319x; 1.1284x over previous
//
#include <hip/hip_runtime.h>

typedef unsigned short u16;
typedef __bf16 bf16x8 __attribute__((ext_vector_type(8)));
typedef float f32x4 __attribute__((ext_vector_type(4)));

// ---------- bf16 <-> f32 helpers (RNE) ----------
__device__ __forceinline__ u16 f2bf(float f) {
    union { float f; unsigned int u; } v; v.f = f;
    unsigned int u = v.u;
    return (u16)((u + 0x7FFFu + ((u >> 16) & 1u)) >> 16);
}
__device__ __forceinline__ float bf2f(u16 h) {
    union { unsigned int u; float f; } v; v.u = ((unsigned int)h) << 16;
    return v.f;
}

// ---------- async global->LDS, 16B per lane ----------
__device__ __forceinline__ void load_lds16(const void* g, void* l) {
    __builtin_amdgcn_global_load_lds(
        (const __attribute__((address_space(1))) unsigned int*)g,
        (__attribute__((address_space(3))) unsigned int*)l,
        16, 0, 0);
}

// ---------------------------------------------------------------
// prep: cast x (fp32) -> bf16
// ---------------------------------------------------------------
__global__ void __launch_bounds__(256) cast_x_kernel(const float4* __restrict__ X,
                                                     u16* __restrict__ out) {
    int idx = blockIdx.x * 256 + threadIdx.x;
    float4 v = X[idx];
    ushort4 o;
    o.x = f2bf(v.x); o.y = f2bf(v.y); o.z = f2bf(v.z); o.w = f2bf(v.w);
    *(ushort4*)(out + (size_t)idx * 4) = o;
}

// ---------------------------------------------------------------
// prep: transpose + cast W [1024,1024] fp32 -> Wt [n][k] bf16
// ---------------------------------------------------------------
__global__ void __launch_bounds__(256) transpose_w_kernel(
    const float* __restrict__ W0, const float* __restrict__ W1, const float* __restrict__ W2,
    u16* __restrict__ O0, u16* __restrict__ O1, u16* __restrict__ O2) {
    const float* W = (blockIdx.z == 0) ? W0 : (blockIdx.z == 1) ? W1 : W2;
    u16* O = (blockIdx.z == 0) ? O0 : (blockIdx.z == 1) ? O1 : O2;
    __shared__ float tile[32][33];
    int tx = threadIdx.x, ty = threadIdx.y;
    int n0 = blockIdx.x * 32, k0 = blockIdx.y * 32;
    #pragma unroll
    for (int j = 0; j < 32; j += 8)
        tile[ty + j][tx] = W[(size_t)(k0 + ty + j) * 1024 + n0 + tx];
    __syncthreads();
    #pragma unroll
    for (int j = 0; j < 32; j += 8)
        O[(size_t)(n0 + ty + j) * 1024 + k0 + tx] = f2bf(tile[tx][ty + j]);
}

// ---------------------------------------------------------------
// NT bf16 GEMM, 128x128 tile, BK=64, XOR-swizzled LDS (conflict-free).
// All modes decode (z, mtile, ntile) from a linear blockIdx so that
// blocks sharing an A-tile have equal (linear&7) -> same XCD L2.
//
// MODE 0: merged QKV. z selects B (WqT/WkT/WvT) and C (Q / K / Vt).
// MODE 1: P~ = exp(scores*cscale - 12), live causal tiles only,
//         + per-row sum atomicAdd into rowsum (fp32).
// MODE 3: PV, fp32 out, K-loop causally clipped, /rowsum epilogue.
// ---------------------------------------------------------------
template <int MODE>
__global__ void __launch_bounds__(256) gemm_nt(
    const u16* __restrict__ A, const u16* __restrict__ Bq,
    const u16* __restrict__ Bk, const u16* __restrict__ Bv,
    void* __restrict__ Cq, void* __restrict__ Ck, void* __restrict__ Cv,
    float* __restrict__ rowsum,
    int N, int K, long sA, long sB, long sC, float cscale) {
    int mtile, ntile, z;
    if (MODE == 0) {
        // pair p = z*64+mtile clustered on XCD p&7 (== mtile&7)
        int L = blockIdx.x;
        int c = L & 7, t = (L >> 3) & 7, hi = L >> 6;
        int p = hi * 8 + c;
        z = p >> 6; mtile = p & 63; ntile = t;
    } else if (MODE == 1) {
        // live causal tiles only; row-group m clustered on XCD m&7
        int c = blockIdx.x & 7, g = blockIdx.x >> 3;
        z = blockIdx.z;
        if (g <= c)               { mtile = c;     ntile = g; }
        else if (g < 2 * c + 10)  { mtile = c + 8; ntile = g - (c + 1); }
        else return;
    } else {
        // pair p = z*16+mtile clustered on XCD p&7
        int L = blockIdx.x;
        int c = L & 7, x = (L >> 3) & 7, hi = L >> 6;
        int p = hi * 8 + c;
        z = p >> 4; mtile = p & 15; ntile = x;
    }

    const u16* B;
    if (MODE == 0) {
        B = (z == 0) ? Bq : (z == 1) ? Bk : Bv;
    } else {
        B = Bq + (size_t)z * sB;
        A += (size_t)z * sA;
    }

    __shared__ __align__(16) u16 As[2][128 * 32];
    __shared__ __align__(16) u16 Bs[2][128 * 32];

    const int tid = threadIdx.x;
    const int lane = tid & 63;
    const int wave = tid >> 6;
    const int wr = wave >> 1, wc = wave & 1;

    int kiters = K >> 6;                      // BK = 64
    if (MODE == 3) kiters = (mtile + 1) * 2;  // causal clip (BM=128)

    const int r0 = tid >> 2;
    const int kb = (((tid & 3) ^ ((r0 >> 1) & 3))) * 16;  // swizzled 16B chunk

    const char* gA0 = (const char*)(A + (size_t)(mtile * 128 + r0) * K) + kb;
    const char* gA1 = gA0 + (size_t)64 * K * 2;
    const char* gB0 = (const char*)(B + (size_t)(ntile * 128 + r0) * K) + kb;
    const char* gB1 = gB0 + (size_t)64 * K * 2;

    char* lA = (char*)(&As[0][0]) + tid * 16;
    char* lB = (char*)(&Bs[0][0]) + tid * 16;

    f32x4 acc[4][4] = {};

    const int quad = lane >> 4;
    const int l16 = lane & 15;
    const int ch = quad ^ ((l16 >> 1) & 3);   // de-swizzle on read
    const int aoff = (wr * 64 + l16) * 32 + ch * 8;
    const int boff = (wc * 64 + l16) * 32 + ch * 8;

    for (int kt = 0; kt < kiters; ++kt) {
        load_lds16(gA0,      lA);
        load_lds16(gA1,      lA + 4096);
        load_lds16(gA0 + 64, lA + 8192);
        load_lds16(gA1 + 64, lA + 12288);
        load_lds16(gB0,      lB);
        load_lds16(gB1,      lB + 4096);
        load_lds16(gB0 + 64, lB + 8192);
        load_lds16(gB1 + 64, lB + 12288);
        gA0 += 128; gA1 += 128; gB0 += 128; gB1 += 128;
        __syncthreads();

        #pragma unroll
        for (int h = 0; h < 2; ++h) {
            const u16* ap = &As[h][aoff];
            const u16* bp = &Bs[h][boff];
            bf16x8 af[4], bfv[4];
            #pragma unroll
            for (int r = 0; r < 4; ++r) af[r] = *(const bf16x8*)(ap + r * 512);
            #pragma unroll
            for (int c = 0; c < 4; ++c) bfv[c] = *(const bf16x8*)(bp + c * 512);
            #pragma unroll
            for (int r = 0; r < 4; ++r)
                #pragma unroll
                for (int c = 0; c < 4; ++c)
                    acc[r][c] = __builtin_amdgcn_mfma_f32_16x16x32_bf16(af[r], bfv[c], acc[r][c], 0, 0, 0);
        }
        __syncthreads();
    }

    // epilogue — C/D layout: col = lane&15, row = (lane>>4)*4 + reg
    const int grow0 = mtile * 128 + wr * 64 + quad * 4;
    const int gcol0 = ntile * 128 + wc * 64 + l16;

    if (MODE == 0) {
        if (z < 2) {
            u16* C = (u16*)((z == 0) ? Cq : Ck);
            #pragma unroll
            for (int r = 0; r < 4; ++r)
                #pragma unroll
                for (int c = 0; c < 4; ++c)
                    #pragma unroll
                    for (int i = 0; i < 4; ++i)
                        C[(size_t)(grow0 + r * 16 + i) * N + gcol0 + c * 16] =
                            f2bf(acc[r][c][i]);
        } else {
            // Vt[b][d][s]: m -> (b, s), n -> d
            u16* C = (u16*)Cv;
            #pragma unroll
            for (int r = 0; r < 4; ++r) {
                int m0 = grow0 + r * 16;
                int b = m0 >> 11, s0 = m0 & 2047;
                #pragma unroll
                for (int c = 0; c < 4; ++c) {
                    int d = gcol0 + c * 16;
                    ushort4 o;
                    o.x = f2bf(acc[r][c][0]); o.y = f2bf(acc[r][c][1]);
                    o.z = f2bf(acc[r][c][2]); o.w = f2bf(acc[r][c][3]);
                    *(ushort4*)(C + (size_t)b * (1024 * 2048) + (size_t)d * 2048 + s0) = o;
                }
            }
        }
    } else if (MODE == 1) {
        u16* C = (u16*)Cq + (size_t)z * sC;
        float* rs = rowsum + z * 2048;
        const bool diag = (ntile == mtile);
        float rsum[4][4];
        #pragma unroll
        for (int r = 0; r < 4; ++r)
            #pragma unroll
            for (int i = 0; i < 4; ++i) rsum[r][i] = 0.f;
        #pragma unroll
        for (int r = 0; r < 4; ++r)
            #pragma unroll
            for (int c = 0; c < 4; ++c)
                #pragma unroll
                for (int i = 0; i < 4; ++i) {
                    int grow = grow0 + r * 16 + i;
                    int gcol = gcol0 + c * 16;
                    float e = 0.f;
                    if (!diag || gcol <= grow)
                        e = __expf(acc[r][c][i] * cscale - 12.0f);
                    C[(size_t)grow * N + gcol] = f2bf(e);
                    rsum[r][i] += e;
                }
        #pragma unroll
        for (int r = 0; r < 4; ++r)
            #pragma unroll
            for (int i = 0; i < 4; ++i) {
                float s = rsum[r][i];
                s += __shfl_xor(s, 1, 64);
                s += __shfl_xor(s, 2, 64);
                s += __shfl_xor(s, 4, 64);
                s += __shfl_xor(s, 8, 64);
                if (l16 == 0)
                    atomicAdd(&rs[grow0 + r * 16 + i], s);
            }
    } else {  // MODE 3: divide by row sum
        float* C = (float*)Cq + (size_t)z * sC;
        const float* rs = rowsum + z * 2048;
        #pragma unroll
        for (int r = 0; r < 4; ++r)
            #pragma unroll
            for (int i = 0; i < 4; ++i) {
                int grow = grow0 + r * 16 + i;
                float inv = 1.0f / rs[grow];
                #pragma unroll
                for (int c = 0; c < 4; ++c)
                    C[(size_t)grow * N + gcol0 + c * 16] = acc[r][c][i] * inv;
            }
    }
}

// ---------------------------------------------------------------
// launch
// ---------------------------------------------------------------
extern "C" void kernel_launch(void* const* d_in, const int* in_sizes, int n_in,
                              void* d_out, int out_size, void* d_ws, size_t ws_size,
                              hipStream_t stream) {
    const float* x  = (const float*)d_in[0];
    const float* Wq = (const float*)d_in[1];
    const float* Wk = (const float*)d_in[2];
    const float* Wv = (const float*)d_in[3];
    float* out = (float*)d_out;
    char* ws = (char*)d_ws;
    const size_t Mi = 1u << 20;

    u16* xb  = (u16*)(ws);               // [8192][1024] bf16  16 MiB
    u16* WqT = (u16*)(ws + 16 * Mi);     // [1024][1024] bf16   2 MiB (reused as rowsum after QKV)
    u16* WkT = (u16*)(ws + 18 * Mi);
    u16* WvT = (u16*)(ws + 20 * Mi);
    u16* Q   = (u16*)(ws + 22 * Mi);     // [8192][1024] bf16  16 MiB
    u16* Kb  = (u16*)(ws + 38 * Mi);
    u16* Vt  = (u16*)(ws + 54 * Mi);     // [4][1024][2048] bf16 16 MiB
    u16* S   = (u16*)(ws + 70 * Mi);     // [4][2048][2048] bf16 32 MiB (P~)
    float* rowsum = (float*)(ws + 16 * Mi);  // 4*2048 fp32 = 32 KiB, aliases WqT (dead after QKV)

    cast_x_kernel<<<8192, 256, 0, stream>>>((const float4*)x, xb);
    transpose_w_kernel<<<dim3(32, 32, 3), dim3(32, 8), 0, stream>>>(
        Wq, Wk, Wv, WqT, WkT, WvT);

    // merged QKV projections, XCD-clustered decode, 1536 blocks
    gemm_nt<0><<<dim3(1536, 1, 1), 256, 0, stream>>>(
        xb, WqT, WkT, WvT, Q, Kb, Vt, nullptr, 1024, 1024, 0, 0, 0, 1.f);

    // rowsum := 0 (WqT is dead from here on; stream order guarantees safety)
    hipMemsetAsync(rowsum, 0, 4 * 2048 * sizeof(float), stream);

    // P~ = exp(Q K^T / 32 - 12), live causal tiles only, + rowsum atomics
    gemm_nt<1><<<dim3(192, 1, 4), 256, 0, stream>>>(
        Q, Kb, nullptr, nullptr, S, nullptr, nullptr, rowsum, 2048, 1024,
        (long)2048 * 1024, (long)2048 * 1024, (long)2048 * 2048, 0.03125f);

    // O = (P~ V) / rowsum  (K-loop causally clipped)
    gemm_nt<3><<<dim3(512, 1, 1), 256, 0, stream>>>(
        S, Vt, nullptr, nullptr, out, nullptr, nullptr, rowsum, 1024, 2048,
        (long)2048 * 2048, (long)1024 * 2048, (long)2048 * 1024, 1.f);
}

// Round 4
// 231.080 us; speedup vs baseline: 1.3691x; 1.0279x over previous
//
#include <hip/hip_runtime.h>

typedef unsigned short u16;
typedef __bf16 bf16x8 __attribute__((ext_vector_type(8)));
typedef float f32x4 __attribute__((ext_vector_type(4)));

// ---------- bf16 <-> f32 helpers (RNE) ----------
__device__ __forceinline__ u16 f2bf(float f) {
    union { float f; unsigned int u; } v; v.f = f;
    unsigned int u = v.u;
    return (u16)((u + 0x7FFFu + ((u >> 16) & 1u)) >> 16);
}

// ---------- async global->LDS, 16B per lane ----------
__device__ __forceinline__ void load_lds16(const void* g, void* l) {
    __builtin_amdgcn_global_load_lds(
        (const __attribute__((address_space(1))) unsigned int*)g,
        (__attribute__((address_space(3))) unsigned int*)l,
        16, 0, 0);
}

// ---------------------------------------------------------------
// fused prep: blocks 0..8191 cast x fp32->bf16; blocks 8192..11263
// transpose+cast Wq/Wk/Wv -> Wt[n][k] bf16.
// ---------------------------------------------------------------
__global__ void __launch_bounds__(256) prep_kernel(
    const float4* __restrict__ X, u16* __restrict__ xb,
    const float* __restrict__ Wq, const float* __restrict__ Wk,
    const float* __restrict__ Wv,
    u16* __restrict__ Oq, u16* __restrict__ Ok, u16* __restrict__ Ov) {
    __shared__ float tile[32][33];
    const int bid = blockIdx.x, tid = threadIdx.x;
    if (bid < 8192) {
        int idx = bid * 256 + tid;
        float4 v = X[idx];
        ushort4 o;
        o.x = f2bf(v.x); o.y = f2bf(v.y); o.z = f2bf(v.z); o.w = f2bf(v.w);
        *(ushort4*)(xb + (size_t)idx * 4) = o;
    } else {
        int id = bid - 8192;                 // 0..3071
        int zz = id >> 10;
        const float* W = (zz == 0) ? Wq : (zz == 1) ? Wk : Wv;
        u16* O = (zz == 0) ? Oq : (zz == 1) ? Ok : Ov;
        int n0 = (id & 31) * 32, k0 = ((id >> 5) & 31) * 32;
        int tx = tid & 31, ty = tid >> 5;    // 32x8
        #pragma unroll
        for (int j = 0; j < 32; j += 8)
            tile[ty + j][tx] = W[(size_t)(k0 + ty + j) * 1024 + n0 + tx];
        __syncthreads();
        #pragma unroll
        for (int j = 0; j < 32; j += 8)
            O[(size_t)(n0 + ty + j) * 1024 + k0 + tx] = f2bf(tile[tx][ty + j]);
    }
}

// ---------------------------------------------------------------
// NT bf16 GEMM, 128x128 tile, BK=64, XOR-swizzled LDS (conflict-free),
// XCD-clustered linear block decodes (blocks sharing an A-tile have the
// same (linear&7) -> same XCD L2).
//
// MODE 0: Q,K projections. z in {0,1} selects Wq/Wk and Q/Kb.
// MODE 1: merged dispatch. blocks <512: V-projection (Vt[b][d][s] store);
//         blocks >=512: P~ = exp(QK^T/32 - 12) into S, live causal
//         tiles only, masked entries written as 0.
// MODE 3: O = (P~ V) / rowsum. kiters causally clipped; rowsum computed
//         IN-KERNEL via extra MFMAs against a ones B-fragment (the
//         16x16x32 C/D layout maps acc_rs[r][i] to exactly the epilogue's
//         (r,i) rows). Heavy tiles dispatched first.
// ---------------------------------------------------------------
template <int MODE>
__global__ void __launch_bounds__(256) gemm_nt(
    const u16* __restrict__ xb, const u16* __restrict__ WqT,
    const u16* __restrict__ WkT, const u16* __restrict__ WvT,
    u16* __restrict__ Q, u16* __restrict__ Kb,
    u16* __restrict__ Vt, u16* __restrict__ S,
    float* __restrict__ out) {

    int mtile, ntile, z;
    const u16 *A, *B;
    int vsub = 0;

    if (MODE == 0) {
        int L = blockIdx.x;                       // 1024 blocks
        int c = L & 7, t = (L >> 3) & 7, hi = L >> 6;
        int p = hi * 8 + c;                       // 0..127, cluster = mtile&7
        z = p >> 6; mtile = p & 63; ntile = t;
        A = xb;
        B = z ? WkT : WqT;
    } else if (MODE == 1) {
        if (blockIdx.x < 512) {                   // V-projection
            vsub = 1;
            int id = blockIdx.x;
            int c = id & 7, t = (id >> 3) & 7, hi = id >> 6;
            mtile = hi * 8 + c; ntile = t; z = 0;
            A = xb; B = WvT;
        } else {                                  // scores, live tiles
            int id2 = blockIdx.x - 512;           // 0..767
            z = id2 / 192;
            int r = id2 - z * 192;
            int c = r & 7, g = r >> 3;
            if (g <= c)            { mtile = c;     ntile = g; }
            else if (g < 2*c + 10) { mtile = c + 8; ntile = g - (c + 1); }
            else return;
            A = Q  + (size_t)z * (2048 * 1024);
            B = Kb + (size_t)z * (2048 * 1024);
        }
    } else {
        int L = blockIdx.x;                       // 512 blocks
        int c = L & 7, j = (L >> 3) & 7, h = L >> 6;
        int P = h * 8 + c;                        // 0..63; same(z,mtile)->same c
        z = P & 3; mtile = 15 - (P >> 2); ntile = j;   // heavy-first
        A = S  + (size_t)z * (2048 * 2048);
        B = Vt + (size_t)z * (1024 * 2048);
    }

    const int LDA = (MODE == 3) ? 2048 : 1024;
    const int kiters = (MODE == 3) ? (mtile + 1) * 2 : 16;   // BK=64

    __shared__ __align__(16) u16 As[2][128 * 32];
    __shared__ __align__(16) u16 Bs[2][128 * 32];

    const int tid = threadIdx.x;
    const int lane = tid & 63;
    const int wave = tid >> 6;
    const int wr = wave >> 1, wc = wave & 1;

    const int r0 = tid >> 2;
    const int kb = (((tid & 3) ^ ((r0 >> 1) & 3))) * 16;   // swizzled 16B chunk

    const char* gA0 = (const char*)(A + (size_t)(mtile * 128 + r0) * LDA) + kb;
    const char* gA1 = gA0 + (size_t)64 * LDA * 2;
    const char* gB0 = (const char*)(B + (size_t)(ntile * 128 + r0) * LDA) + kb;
    const char* gB1 = gB0 + (size_t)64 * LDA * 2;

    char* lA = (char*)(&As[0][0]) + tid * 16;
    char* lB = (char*)(&Bs[0][0]) + tid * 16;

    f32x4 acc[4][4] = {};
    f32x4 acc_rs[4] = {};   // MODE 3 row sums (dead otherwise)

    bf16x8 vones;
    #pragma unroll
    for (int i = 0; i < 8; ++i) vones[i] = (__bf16)1.0f;

    const int quad = lane >> 4;
    const int l16 = lane & 15;
    const int ch = quad ^ ((l16 >> 1) & 3);   // de-swizzle on read
    const int aoff = (wr * 64 + l16) * 32 + ch * 8;
    const int boff = (wc * 64 + l16) * 32 + ch * 8;

    for (int kt = 0; kt < kiters; ++kt) {
        load_lds16(gA0,      lA);
        load_lds16(gA1,      lA + 4096);
        load_lds16(gA0 + 64, lA + 8192);
        load_lds16(gA1 + 64, lA + 12288);
        load_lds16(gB0,      lB);
        load_lds16(gB1,      lB + 4096);
        load_lds16(gB0 + 64, lB + 8192);
        load_lds16(gB1 + 64, lB + 12288);
        gA0 += 128; gA1 += 128; gB0 += 128; gB1 += 128;
        __syncthreads();

        #pragma unroll
        for (int h2 = 0; h2 < 2; ++h2) {
            const u16* ap = &As[h2][aoff];
            const u16* bp = &Bs[h2][boff];
            bf16x8 af[4], bfv[4];
            #pragma unroll
            for (int r = 0; r < 4; ++r) af[r] = *(const bf16x8*)(ap + r * 512);
            #pragma unroll
            for (int c = 0; c < 4; ++c) bfv[c] = *(const bf16x8*)(bp + c * 512);
            if (MODE == 3) {
                #pragma unroll
                for (int r = 0; r < 4; ++r)
                    acc_rs[r] = __builtin_amdgcn_mfma_f32_16x16x32_bf16(
                        af[r], vones, acc_rs[r], 0, 0, 0);
            }
            #pragma unroll
            for (int r = 0; r < 4; ++r)
                #pragma unroll
                for (int c = 0; c < 4; ++c)
                    acc[r][c] = __builtin_amdgcn_mfma_f32_16x16x32_bf16(
                        af[r], bfv[c], acc[r][c], 0, 0, 0);
        }
        __syncthreads();
    }

    // epilogue — C/D layout: col = lane&15, row = (lane>>4)*4 + reg
    const int grow0 = mtile * 128 + wr * 64 + quad * 4;
    const int gcol0 = ntile * 128 + wc * 64 + l16;

    if (MODE == 0) {
        u16* C = z ? Kb : Q;
        #pragma unroll
        for (int r = 0; r < 4; ++r)
            #pragma unroll
            for (int c = 0; c < 4; ++c)
                #pragma unroll
                for (int i = 0; i < 4; ++i)
                    C[(size_t)(grow0 + r * 16 + i) * 1024 + gcol0 + c * 16] =
                        f2bf(acc[r][c][i]);
    } else if (MODE == 1) {
        if (vsub) {
            // Vt[b][d][s]: m -> (b,s), n -> d; 4 consecutive i -> consecutive s
            #pragma unroll
            for (int r = 0; r < 4; ++r) {
                int m0 = grow0 + r * 16;
                int b = m0 >> 11, s0 = m0 & 2047;
                #pragma unroll
                for (int c = 0; c < 4; ++c) {
                    int d = gcol0 + c * 16;
                    ushort4 o;
                    o.x = f2bf(acc[r][c][0]); o.y = f2bf(acc[r][c][1]);
                    o.z = f2bf(acc[r][c][2]); o.w = f2bf(acc[r][c][3]);
                    *(ushort4*)(Vt + (size_t)b * (1024 * 2048) + (size_t)d * 2048 + s0) = o;
                }
            }
        } else {
            u16* C = S + (size_t)z * (2048 * 2048);
            const bool diag = (ntile == mtile);
            #pragma unroll
            for (int r = 0; r < 4; ++r)
                #pragma unroll
                for (int c = 0; c < 4; ++c)
                    #pragma unroll
                    for (int i = 0; i < 4; ++i) {
                        int grow = grow0 + r * 16 + i;
                        int gcol = gcol0 + c * 16;
                        float e = 0.f;
                        if (!diag || gcol <= grow)
                            e = __expf(acc[r][c][i] * 0.03125f - 12.0f);
                        C[(size_t)grow * 2048 + gcol] = f2bf(e);
                    }
        }
    } else {  // MODE 3: normalize by in-kernel row sums
        float* C = out + (size_t)z * (2048 * 1024);
        #pragma unroll
        for (int r = 0; r < 4; ++r)
            #pragma unroll
            for (int i = 0; i < 4; ++i) {
                int grow = grow0 + r * 16 + i;
                float inv = 1.0f / acc_rs[r][i];
                #pragma unroll
                for (int c = 0; c < 4; ++c)
                    C[(size_t)grow * 1024 + gcol0 + c * 16] = acc[r][c][i] * inv;
            }
    }
}

// ---------------------------------------------------------------
// launch
// ---------------------------------------------------------------
extern "C" void kernel_launch(void* const* d_in, const int* in_sizes, int n_in,
                              void* d_out, int out_size, void* d_ws, size_t ws_size,
                              hipStream_t stream) {
    const float* x  = (const float*)d_in[0];
    const float* Wq = (const float*)d_in[1];
    const float* Wk = (const float*)d_in[2];
    const float* Wv = (const float*)d_in[3];
    float* out = (float*)d_out;
    char* ws = (char*)d_ws;
    const size_t Mi = 1u << 20;

    u16* xb  = (u16*)(ws);               // [8192][1024] bf16  16 MiB
    u16* WqT = (u16*)(ws + 16 * Mi);     // [1024][1024] bf16   2 MiB
    u16* WkT = (u16*)(ws + 18 * Mi);
    u16* WvT = (u16*)(ws + 20 * Mi);
    u16* Q   = (u16*)(ws + 22 * Mi);     // [8192][1024] bf16  16 MiB
    u16* Kb  = (u16*)(ws + 38 * Mi);
    u16* Vt  = (u16*)(ws + 54 * Mi);     // [4][1024][2048] bf16 16 MiB
    u16* S   = (u16*)(ws + 70 * Mi);     // [4][2048][2048] bf16 32 MiB (P~)

    // prep: cast x + transpose W (fused)
    prep_kernel<<<11264, 256, 0, stream>>>(
        (const float4*)x, xb, Wq, Wk, Wv, WqT, WkT, WvT);

    // Q,K projections only (V moved into next dispatch)
    gemm_nt<0><<<1024, 256, 0, stream>>>(xb, WqT, WkT, WvT, Q, Kb, Vt, S, out);

    // merged: V-projection (512 blocks) + P~ scores (768 blocks, live causal)
    gemm_nt<1><<<1280, 256, 0, stream>>>(xb, WqT, WkT, WvT, Q, Kb, Vt, S, out);

    // O = (P~ V)/rowsum, rowsum via ones-MFMA, heavy tiles first
    gemm_nt<3><<<512, 256, 0, stream>>>(xb, WqT, WkT, WvT, Q, Kb, Vt, S, out);
}